// Round 5
// baseline (59397.711 us; speedup 1.0000x reference)
//
#include <hip/hip_runtime.h>
#include <hip/hip_bf16.h>

typedef __hip_bfloat16 bf16;

#define TM 64
#define TN 64
#define TK 16
#define LDP 68  // padded leading dim; 2-way bank aliasing max (free per m136)

__device__ __forceinline__ float ldE(const float* p) { return *p; }
__device__ __forceinline__ float ldE(const bf16* p)  { return (float)*p; }
__device__ __forceinline__ void stC(float* p, float v) { *p = v; }
__device__ __forceinline__ void stC(bf16* p, float v)  { *p = __float2bfloat16(v); }

// NaN-proof activations: clamp is a no-op on correct data (|preact| <~ 5) and
// sanitizes any garbage; exp forms are finite for all clamped inputs.
__device__ __forceinline__ float sigm(float x) {
    x = fminf(fmaxf(x, -40.f), 40.f);
    return 1.f / (1.f + expf(-x));
}
__device__ __forceinline__ float tanh_s(float x) {
    x = fminf(fmaxf(x, -20.f), 20.f);
    float e = expf(2.f * x);
    return 1.f - 2.f / (e + 1.f);
}

// C[d] = A[d] (MxK, row-major) @ W[d]^T   (W is NcxK, row-major)
template <typename AT, typename WT, typename CT>
__global__ __launch_bounds__(256) void gemm_aw(
    const AT* __restrict__ A, long sAd,
    const WT* __restrict__ W, long sWd,
    CT* __restrict__ C, long sCd,
    int M, int Nc, int K)
{
    __shared__ alignas(16) float As[TK][LDP];
    __shared__ alignas(16) float Ws[TK][LDP];
    const int d = blockIdx.z;
    A += (long)d * sAd; W += (long)d * sWd; C += (long)d * sCd;
    const int m0 = blockIdx.y * TM;
    const int n0 = blockIdx.x * TN;
    const int tid = threadIdx.x;
    const int tx = tid & 15, ty = tid >> 4;

    float acc[4][4] = {};
    for (int k0 = 0; k0 < K; k0 += TK) {
#pragma unroll
        for (int i = 0; i < 4; ++i) {
            int e = tid + i * 256;       // 0..1023
            int m = e >> 4;              // 0..63
            int kk = e & 15;             // 0..15
            float va = 0.f, vw = 0.f;
            if (m0 + m < M && k0 + kk < K) va = ldE(&A[(long)(m0 + m) * K + k0 + kk]);
            if (n0 + m < Nc && k0 + kk < K) vw = ldE(&W[(long)(n0 + m) * K + k0 + kk]);
            As[kk][m] = va;
            Ws[kk][m] = vw;
        }
        __syncthreads();
#pragma unroll
        for (int kk = 0; kk < TK; ++kk) {
            float4 a4 = *reinterpret_cast<const float4*>(&As[kk][ty * 4]);
            float4 b4 = *reinterpret_cast<const float4*>(&Ws[kk][tx * 4]);
            float a[4] = {a4.x, a4.y, a4.z, a4.w};
            float b[4] = {b4.x, b4.y, b4.z, b4.w};
#pragma unroll
            for (int i = 0; i < 4; ++i)
#pragma unroll
                for (int j = 0; j < 4; ++j)
                    acc[i][j] += a[i] * b[j];
        }
        __syncthreads();
    }
#pragma unroll
    for (int i = 0; i < 4; ++i) {
        int m = m0 + ty * 4 + i;
        if (m >= M) continue;
#pragma unroll
        for (int j = 0; j < 4; ++j) {
            int n = n0 + tx * 4 + j;
            if (n < Nc) stC(&C[(long)m * Nc + n], acc[i][j]);
        }
    }
}

// Word layer-0 GRU step: input gates gathered from embW[tok] (= emb @ Wih0^T).
__global__ void gru_step_word0(
    const int* __restrict__ x,      // [S,T,B]
    const bf16* __restrict__ embW,  // [2, V, 3H]
    const float* __restrict__ gh,   // [2, N, 3H]
    const float* __restrict__ bih,  // [2, 3H]
    const float* __restrict__ bhh,  // [2, 3H]
    float* __restrict__ h,          // [2, N, H]
    bf16* __restrict__ y,           // [T, N, 2H]
    int S, int T, int B, int V, int H, int k)
{
    const int N = S * B;
    long idx = (long)blockIdx.x * 256 + threadIdx.x;
    if (idx >= 2ll * N * H) return;
    int j = idx % H;
    int n = (idx / H) % N;
    int d = idx / ((long)N * H);
    int G = 3 * H;
    int t_eff = (d == 0) ? k : (T - 1 - k);
    int s = n / B, b = n % B;
    int tok = x[((long)s * T + t_eff) * B + b];
    tok = max(0, min(V - 1, tok));   // crash-safety; x is in-range per reference

    const bf16*  xp = embW + ((long)d * V + tok) * G;
    const float* gp = gh + ((long)d * N + n) * G;
    const float* bi = bih + (long)d * G;
    const float* bh = bhh + (long)d * G;

    float xr = (float)xp[j]         + bi[j];
    float xz = (float)xp[H + j]     + bi[H + j];
    float xn = (float)xp[2 * H + j] + bi[2 * H + j];
    float hr = gp[j]         + bh[j];
    float hz = gp[H + j]     + bh[H + j];
    float hn = gp[2 * H + j] + bh[2 * H + j];

    float r = sigm(xr + hr);
    float z = sigm(xz + hz);
    float nn = tanh_s(xn + r * hn);

    long hidx = ((long)d * N + n) * H + j;
    float hnew = (1.f - z) * nn + z * h[hidx];
    h[hidx] = hnew;
    y[((long)t_eff * N + n) * (2 * H) + (long)d * H + j] = __float2bfloat16(hnew);
}

// Generic GRU step; xw holds ONE timestep per direction: [2, N, 3H].
__global__ void gru_step1(
    const bf16* __restrict__ xw,   // [2, N, 3H] input gates (no bias)
    const float* __restrict__ gh,  // [2, N, 3H] h @ Whh^T   (no bias)
    const float* __restrict__ bih, // [2, 3H]
    const float* __restrict__ bhh, // [2, 3H]
    float* __restrict__ h,         // [2, N, H]
    bf16* __restrict__ y,          // [L, N, 2H] or nullptr
    int N, int H, int L, int k)
{
    long idx = (long)blockIdx.x * 256 + threadIdx.x;
    if (idx >= 2ll * N * H) return;
    int j = idx % H;
    int n = (idx / H) % N;
    int d = idx / ((long)N * H);
    int G = 3 * H;
    int t_eff = (d == 0) ? k : (L - 1 - k);

    const bf16*  xp = xw + ((long)d * N + n) * G;
    const float* gp = gh + ((long)d * N + n) * G;
    const float* bi = bih + (long)d * G;
    const float* bh = bhh + (long)d * G;

    float xr = (float)xp[j]         + bi[j];
    float xz = (float)xp[H + j]     + bi[H + j];
    float xn = (float)xp[2 * H + j] + bi[2 * H + j];
    float hr = gp[j]         + bh[j];
    float hz = gp[H + j]     + bh[H + j];
    float hn = gp[2 * H + j] + bh[2 * H + j];

    float r = sigm(xr + hr);
    float z = sigm(xz + hz);
    float nn = tanh_s(xn + r * hn);

    long hidx = ((long)d * N + n) * H + j;
    float hnew = (1.f - z) * nn + z * h[hidx];
    h[hidx] = hnew;
    if (y) y[((long)t_eff * N + n) * (2 * H) + (long)d * H + j] = __float2bfloat16(hnew);
}

// out[n, 4H] = [ha_d0 | ha_d1 | hb_d0 | hb_d1]  — OUT dtype templated
template <typename OT>
__global__ void concat4(const float* __restrict__ ha, const float* __restrict__ hb,
                        OT* __restrict__ out, int N, int H)
{
    long idx = (long)blockIdx.x * 256 + threadIdx.x;
    int C4 = 4 * H;
    if (idx >= (long)N * C4) return;
    int c = idx % C4;
    long n = idx / C4;
    int blk = c / H, j = c % H;
    const float* src = (blk < 2) ? ha : hb;
    int dd = blk & 1;
    stC(&out[idx], src[((long)dd * N + n) * H + j]);
}

extern "C" void kernel_launch(void* const* d_in, const int* in_sizes, int n_in,
                              void* d_out, int out_size, void* d_ws, size_t ws_size,
                              hipStream_t stream)
{
    const int S = 120, T = 10, B = 128, E = 80, HW = 75, HS = 700, V = 30000;
    const int Nw = S * B;            // 15360
    const int Gw = 3 * HW;           // 225
    const int Gs = 3 * HS;           // 2100
    (void)in_sizes; (void)n_in; (void)out_size; (void)ws_size;

    // Inputs: x int32; float params are float32 (reference jnp.float32).
    const int*   x       = (const int*)d_in[0];
    const float* emb     = (const float*)d_in[1];
    const float* we_Wih0 = (const float*)d_in[2],  *we_Whh0 = (const float*)d_in[3];
    const float* we_bih0 = (const float*)d_in[4],  *we_bhh0 = (const float*)d_in[5];
    const float* we_Wih1 = (const float*)d_in[6],  *we_Whh1 = (const float*)d_in[7];
    const float* we_bih1 = (const float*)d_in[8],  *we_bhh1 = (const float*)d_in[9];
    const float* se_Wih0 = (const float*)d_in[10], *se_Whh0 = (const float*)d_in[11];
    const float* se_bih0 = (const float*)d_in[12], *se_bhh0 = (const float*)d_in[13];
    const float* se_Wih1 = (const float*)d_in[14], *se_Whh1 = (const float*)d_in[15];
    const float* se_bih1 = (const float*)d_in[16], *se_bhh1 = (const float*)d_in[17];

    // ---- arena layout, 148,992,000 bytes total, disjoint-lifetime unions ----
    char* ws = (char*)d_ws;
    const size_t szA = 46080000;  // y0w bf16 [T*Nw,150] -> words bf16 [Nw,300]
    const size_t szB = 43008000;  // embW bf16 [2,V,225] -> y0s bf16 [S*B,1400]
    const size_t szC = 27648000;  // gh_w f32 [2,Nw,225] -> gh_s f32 [2,B,2100]
    const size_t szD = 13824000;  // xw_w1 bf16 [2,Nw,225] -> xw_s bf16 [2,B,2100]
    const size_t szE = 9216000;   // h_w0 f32 [2,Nw,75]  -> h_s0 f32 [2,B,700]
    const size_t szF = 9216000;   // h_w1                -> h_s1
    char* pA = ws;
    char* pB = pA + szA;
    char* pC = pB + szB;
    char* pD = pC + szC;
    char* pE = pD + szD;
    char* pF = pE + szE;
    const size_t total = szA + szB + szC + szD + szE + szF;  // 148,992,000

    bf16*  y0w  = (bf16*)pA;   bf16* words = (bf16*)pA;
    bf16*  embW = (bf16*)pB;   bf16* y0s   = (bf16*)pB;
    float* gh_w = (float*)pC;  float* gh_s = (float*)pC;
    bf16*  xw_w1= (bf16*)pD;   bf16* xw_s  = (bf16*)pD;
    float* h_w0 = (float*)pE;  float* h_s0 = (float*)pE;
    float* h_w1 = (float*)pF;  float* h_s1 = (float*)pF;

    // Zero the used workspace: kills 0xAA poison, sets h0=0.
    hipMemsetAsync(ws, 0, total, stream);

    auto grid = [](int M, int Nc) {
        return dim3((Nc + TN - 1) / TN, (M + TM - 1) / TM, 2);
    };

    // ===================== word encoder =====================
    // embW[d] = emb @ Wih0[d]^T : [V,E] x [Gw,E]^T -> [2,V,Gw]
    gemm_aw<float, float, bf16><<<grid(V, Gw), 256, 0, stream>>>(
        emb, 0, we_Wih0, (long)Gw * E, embW, (long)V * Gw, V, Gw, E);
    // ---- layer 0: input gates are a gather from embW ----
    for (int k = 0; k < T; ++k) {
        gemm_aw<float, float, float><<<grid(Nw, Gw), 256, 0, stream>>>(
            h_w0, (long)Nw * HW, we_Whh0, (long)Gw * HW, gh_w, (long)Nw * Gw, Nw, Gw, HW);
        long tot = 2ll * Nw * HW;
        gru_step_word0<<<(tot + 255) / 256, 256, 0, stream>>>(
            x, embW, gh_w, we_bih0, we_bhh0, h_w0, y0w, S, T, B, V, HW, k);
    }
    // ---- layer 1: per-step input GEMM from y0w ----
    for (int k = 0; k < T; ++k) {
        gemm_aw<bf16, float, bf16><<<grid(Nw, Gw), 256, 0, stream>>>(
            y0w + (long)k * Nw * 2 * HW, (long)(T - 1 - 2 * k) * Nw * 2 * HW,
            we_Wih1, (long)Gw * (2 * HW), xw_w1, (long)Nw * Gw, Nw, Gw, 2 * HW);
        gemm_aw<float, float, float><<<grid(Nw, Gw), 256, 0, stream>>>(
            h_w1, (long)Nw * HW, we_Whh1, (long)Gw * HW, gh_w, (long)Nw * Gw, Nw, Gw, HW);
        long tot = 2ll * Nw * HW;
        gru_step1<<<(tot + 255) / 256, 256, 0, stream>>>(
            xw_w1, gh_w, we_bih1, we_bhh1, h_w1, nullptr, Nw, HW, T, k);
    }
    {
        long tot = (long)Nw * 4 * HW;
        concat4<bf16><<<(tot + 255) / 256, 256, 0, stream>>>(h_w0, h_w1, words, Nw, HW);
    }

    // ===================== sentence encoder =====================
    hipMemsetAsync(h_s0, 0, 2ull * B * HS * sizeof(float), stream);
    hipMemsetAsync(h_s1, 0, 2ull * B * HS * sizeof(float), stream);
    // ---- layer 0 ----
    for (int k = 0; k < S; ++k) {
        gemm_aw<bf16, float, bf16><<<grid(B, Gs), 256, 0, stream>>>(
            words + (long)k * B * 4 * HW, (long)(S - 1 - 2 * k) * B * 4 * HW,
            se_Wih0, (long)Gs * (4 * HW), xw_s, (long)B * Gs, B, Gs, 4 * HW);
        gemm_aw<float, float, float><<<grid(B, Gs), 256, 0, stream>>>(
            h_s0, (long)B * HS, se_Whh0, (long)Gs * HS, gh_s, (long)B * Gs, B, Gs, HS);
        long tot = 2ll * B * HS;
        gru_step1<<<(tot + 255) / 256, 256, 0, stream>>>(
            xw_s, gh_s, se_bih0, se_bhh0, h_s0, y0s, B, HS, S, k);
    }
    // ---- layer 1 ----
    for (int k = 0; k < S; ++k) {
        gemm_aw<bf16, float, bf16><<<grid(B, Gs), 256, 0, stream>>>(
            y0s + (long)k * B * 2 * HS, (long)(S - 1 - 2 * k) * B * 2 * HS,
            se_Wih1, (long)Gs * (2 * HS), xw_s, (long)B * Gs, B, Gs, 2 * HS);
        gemm_aw<float, float, float><<<grid(B, Gs), 256, 0, stream>>>(
            h_s1, (long)B * HS, se_Whh1, (long)Gs * HS, gh_s, (long)B * Gs, B, Gs, HS);
        long tot = 2ll * B * HS;
        gru_step1<<<(tot + 255) / 256, 256, 0, stream>>>(
            xw_s, gh_s, se_bih1, se_bhh1, h_s1, nullptr, B, HS, S, k);
    }

    // out[1, B, 4*HS] = [sf0 | sb0 | sf1 | sb1]  -> FLOAT32 (reference output dtype)
    {
        long tot = (long)B * 4 * HS;
        concat4<float><<<(tot + 255) / 256, 256, 0, stream>>>(h_s0, h_s1, (float*)d_out, B, HS);
    }
}

// Round 6
// 15894.545 us; speedup vs baseline: 3.7370x; 3.7370x over previous
//
#include <hip/hip_runtime.h>
#include <hip/hip_bf16.h>

typedef __hip_bfloat16 bf16;

#define TM 64
#define TN 64
#define TK 16
#define LDP 68  // padded leading dim; float4-aligned (stride%4==0), 2-way bank alias max

__device__ __forceinline__ float ldE(const float* p) { return *p; }
__device__ __forceinline__ float ldE(const bf16* p)  { return (float)*p; }
__device__ __forceinline__ void stC(float* p, float v) { *p = v; }
__device__ __forceinline__ void stC(bf16* p, float v)  { *p = __float2bfloat16(v); }

// NaN-proof activations (clamp = no-op on sane data, sanitizes garbage).
__device__ __forceinline__ float sigm(float x) {
    x = fminf(fmaxf(x, -40.f), 40.f);
    return 1.f / (1.f + expf(-x));
}
__device__ __forceinline__ float tanh_s(float x) {
    x = fminf(fmaxf(x, -20.f), 20.f);
    float e = expf(2.f * x);
    return 1.f - 2.f / (e + 1.f);
}

// Batched GEMM: C[d] = A[d] (MxK, row-major) @ W[d]^T (W is NcxK, row-major).
// Used for large, TLP-rich dispatches (many blocks -> latency hidden by waves).
template <typename AT, typename WT, typename CT>
__global__ __launch_bounds__(256) void gemm_aw(
    const AT* __restrict__ A, long sAd,
    const WT* __restrict__ W, long sWd,
    CT* __restrict__ C, long sCd,
    int M, int Nc, int K)
{
    __shared__ alignas(16) float As[TK][LDP];
    __shared__ alignas(16) float Ws[TK][LDP];
    const int d = blockIdx.z;
    A += (long)d * sAd; W += (long)d * sWd; C += (long)d * sCd;
    const int m0 = blockIdx.y * TM;
    const int n0 = blockIdx.x * TN;
    const int tid = threadIdx.x;
    const int tx = tid & 15, ty = tid >> 4;

    float acc[4][4] = {};
    for (int k0 = 0; k0 < K; k0 += TK) {
#pragma unroll
        for (int i = 0; i < 4; ++i) {
            int e = tid + i * 256;
            int m = e >> 4;
            int kk = e & 15;
            float va = 0.f, vw = 0.f;
            if (m0 + m < M && k0 + kk < K) va = ldE(&A[(long)(m0 + m) * K + k0 + kk]);
            if (n0 + m < Nc && k0 + kk < K) vw = ldE(&W[(long)(n0 + m) * K + k0 + kk]);
            As[kk][m] = va;
            Ws[kk][m] = vw;
        }
        __syncthreads();
#pragma unroll
        for (int kk = 0; kk < TK; ++kk) {
            float4 a4 = *reinterpret_cast<const float4*>(&As[kk][ty * 4]);
            float4 b4 = *reinterpret_cast<const float4*>(&Ws[kk][tx * 4]);
            float a[4] = {a4.x, a4.y, a4.z, a4.w};
            float b[4] = {b4.x, b4.y, b4.z, b4.w};
#pragma unroll
            for (int i = 0; i < 4; ++i)
#pragma unroll
                for (int j = 0; j < 4; ++j)
                    acc[i][j] += a[i] * b[j];
        }
        __syncthreads();
    }
#pragma unroll
    for (int i = 0; i < 4; ++i) {
        int m = m0 + ty * 4 + i;
        if (m >= M) continue;
#pragma unroll
        for (int j = 0; j < 4; ++j) {
            int n = n0 + tx * 4 + j;
            if (n < Nc) stC(&C[(long)m * Nc + n], acc[i][j]);
        }
    }
}

// Latency-tolerant step GEMM for the recurrent gh = h @ Whh^T.
// M is assumed a multiple of 32 (M=128 here). 32x64 tile, TK2=32,
// register-prefetch pipeline: global loads for tile k0+TK2 issue before the
// compute on tile k0, so staging latency overlaps VALU even at 1 block/CU.
#define TM2 32
#define TN2 64
#define TK2 32
__global__ __launch_bounds__(256) void gemm_step(
    const float* __restrict__ A, long sAd,   // h state [2, M, K]
    const float* __restrict__ W, long sWd,   // Whh [2, Nc, K]
    float* __restrict__ C, long sCd,         // gh [2, M, Nc]
    int M, int Nc, int K)
{
    __shared__ alignas(16) float As[TK2][TM2 + 4];   // stride 36 (float2-aligned)
    __shared__ alignas(16) float Ws[TK2][TN2 + 4];   // stride 68 (float4-aligned)
    const int d = blockIdx.z;
    A += (long)d * sAd; W += (long)d * sWd; C += (long)d * sCd;
    const int m0 = blockIdx.y * TM2;
    const int n0 = blockIdx.x * TN2;
    const int tid = threadIdx.x;
    const int tx = tid & 15, ty = tid >> 4;

    float ra[4], rw[8];
    auto stage = [&](int k0) {
#pragma unroll
        for (int i = 0; i < 4; ++i) {              // A tile 32x32 = 1024 elems
            int e = tid + i * 256;
            int m = e >> 5, kk = e & 31;
            ra[i] = (k0 + kk < K) ? A[(long)(m0 + m) * K + k0 + kk] : 0.f;
        }
#pragma unroll
        for (int i = 0; i < 8; ++i) {              // W tile 64x32 = 2048 elems
            int e = tid + i * 256;
            int n = e >> 5, kk = e & 31;
            rw[i] = (n0 + n < Nc && k0 + kk < K) ? W[(long)(n0 + n) * K + k0 + kk] : 0.f;
        }
    };

    float acc[2][4] = {};
    stage(0);
    for (int k0 = 0; k0 < K; k0 += TK2) {
#pragma unroll
        for (int i = 0; i < 4; ++i) {
            int e = tid + i * 256;
            As[e & 31][e >> 5] = ra[i];
        }
#pragma unroll
        for (int i = 0; i < 8; ++i) {
            int e = tid + i * 256;
            Ws[e & 31][e >> 5] = rw[i];
        }
        __syncthreads();
        if (k0 + TK2 < K) stage(k0 + TK2);         // prefetch overlaps compute
#pragma unroll
        for (int kk = 0; kk < TK2; ++kk) {
            float2 a2 = *reinterpret_cast<const float2*>(&As[kk][ty * 2]);
            float4 b4 = *reinterpret_cast<const float4*>(&Ws[kk][tx * 4]);
            float a[2] = {a2.x, a2.y};
            float b[4] = {b4.x, b4.y, b4.z, b4.w};
#pragma unroll
            for (int i = 0; i < 2; ++i)
#pragma unroll
                for (int j = 0; j < 4; ++j)
                    acc[i][j] += a[i] * b[j];
        }
        __syncthreads();
    }
#pragma unroll
    for (int i = 0; i < 2; ++i) {
        int m = m0 + ty * 2 + i;                   // m < M by construction (M%32==0)
#pragma unroll
        for (int j = 0; j < 4; ++j) {
            int n = n0 + tx * 4 + j;
            if (n < Nc) C[(long)m * Nc + n] = acc[i][j];
        }
    }
}

// Word layer-0 GRU step: input gates gathered from embW[tok] (= emb @ Wih0^T).
__global__ void gru_step_word0(
    const int* __restrict__ x,      // [S,T,B]
    const bf16* __restrict__ embW,  // [2, V, 3H]
    const float* __restrict__ gh,   // [2, N, 3H]
    const float* __restrict__ bih,  // [2, 3H]
    const float* __restrict__ bhh,  // [2, 3H]
    float* __restrict__ h,          // [2, N, H]
    bf16* __restrict__ y,           // [T, N, 2H]
    int S, int T, int B, int V, int H, int k)
{
    const int N = S * B;
    long idx = (long)blockIdx.x * 256 + threadIdx.x;
    if (idx >= 2ll * N * H) return;
    int j = idx % H;
    int n = (idx / H) % N;
    int d = idx / ((long)N * H);
    int G = 3 * H;
    int t_eff = (d == 0) ? k : (T - 1 - k);
    int s = n / B, b = n % B;
    int tok = x[((long)s * T + t_eff) * B + b];
    tok = max(0, min(V - 1, tok));

    const bf16*  xp = embW + ((long)d * V + tok) * G;
    const float* gp = gh + ((long)d * N + n) * G;
    const float* bi = bih + (long)d * G;
    const float* bh = bhh + (long)d * G;

    float xr = (float)xp[j]         + bi[j];
    float xz = (float)xp[H + j]     + bi[H + j];
    float xn = (float)xp[2 * H + j] + bi[2 * H + j];
    float hr = gp[j]         + bh[j];
    float hz = gp[H + j]     + bh[H + j];
    float hn = gp[2 * H + j] + bh[2 * H + j];

    float r = sigm(xr + hr);
    float z = sigm(xz + hz);
    float nn = tanh_s(xn + r * hn);

    long hidx = ((long)d * N + n) * H + j;
    float hnew = (1.f - z) * nn + z * h[hidx];
    h[hidx] = hnew;
    y[((long)t_eff * N + n) * (2 * H) + (long)d * H + j] = __float2bfloat16(hnew);
}

// Generic GRU step. xw layout [2, Cbuf, N, 3H], indexed by t_local = t_eff - tb_d
// (tb0/tb1 = per-direction t-base of the chunk buffer; Cbuf=1 for per-step).
__global__ void gru_step1(
    const bf16* __restrict__ xw,
    int tb0, int tb1, int Cbuf,
    const float* __restrict__ gh,  // [2, N, 3H]
    const float* __restrict__ bih, // [2, 3H]
    const float* __restrict__ bhh, // [2, 3H]
    float* __restrict__ h,         // [2, N, H]
    bf16* __restrict__ y,          // [L, N, 2H] or nullptr
    int N, int H, int L, int k)
{
    long idx = (long)blockIdx.x * 256 + threadIdx.x;
    if (idx >= 2ll * N * H) return;
    int j = idx % H;
    int n = (idx / H) % N;
    int d = idx / ((long)N * H);
    int G = 3 * H;
    int t_eff = (d == 0) ? k : (L - 1 - k);
    int t_local = t_eff - ((d == 0) ? tb0 : tb1);

    const bf16*  xp = xw + (((long)d * Cbuf + t_local) * N + n) * G;
    const float* gp = gh + ((long)d * N + n) * G;
    const float* bi = bih + (long)d * G;
    const float* bh = bhh + (long)d * G;

    float xr = (float)xp[j]         + bi[j];
    float xz = (float)xp[H + j]     + bi[H + j];
    float xn = (float)xp[2 * H + j] + bi[2 * H + j];
    float hr = gp[j]         + bh[j];
    float hz = gp[H + j]     + bh[H + j];
    float hn = gp[2 * H + j] + bh[2 * H + j];

    float r = sigm(xr + hr);
    float z = sigm(xz + hz);
    float nn = tanh_s(xn + r * hn);

    long hidx = ((long)d * N + n) * H + j;
    float hnew = (1.f - z) * nn + z * h[hidx];
    h[hidx] = hnew;
    if (y) y[((long)t_eff * N + n) * (2 * H) + (long)d * H + j] = __float2bfloat16(hnew);
}

// out[n, 4H] = [ha_d0 | ha_d1 | hb_d0 | hb_d1]
template <typename OT>
__global__ void concat4(const float* __restrict__ ha, const float* __restrict__ hb,
                        OT* __restrict__ out, int N, int H)
{
    long idx = (long)blockIdx.x * 256 + threadIdx.x;
    int C4 = 4 * H;
    if (idx >= (long)N * C4) return;
    int c = idx % C4;
    long n = idx / C4;
    int blk = c / H, j = c % H;
    const float* src = (blk < 2) ? ha : hb;
    int dd = blk & 1;
    stC(&out[idx], src[((long)dd * N + n) * H + j]);
}

extern "C" void kernel_launch(void* const* d_in, const int* in_sizes, int n_in,
                              void* d_out, int out_size, void* d_ws, size_t ws_size,
                              hipStream_t stream)
{
    const int S = 120, T = 10, B = 128, E = 80, HW = 75, HS = 700, V = 30000;
    const int Nw = S * B;            // 15360
    const int Gw = 3 * HW;           // 225
    const int Gs = 3 * HS;           // 2100
    const int CH = 60;               // sentence chunk size (2 chunks of 60 steps)
    (void)in_sizes; (void)n_in; (void)out_size; (void)ws_size;

    const int*   x       = (const int*)d_in[0];
    const float* emb     = (const float*)d_in[1];
    const float* we_Wih0 = (const float*)d_in[2],  *we_Whh0 = (const float*)d_in[3];
    const float* we_bih0 = (const float*)d_in[4],  *we_bhh0 = (const float*)d_in[5];
    const float* we_Wih1 = (const float*)d_in[6],  *we_Whh1 = (const float*)d_in[7];
    const float* we_bih1 = (const float*)d_in[8],  *we_bhh1 = (const float*)d_in[9];
    const float* se_Wih0 = (const float*)d_in[10], *se_Whh0 = (const float*)d_in[11];
    const float* se_bih0 = (const float*)d_in[12], *se_bhh0 = (const float*)d_in[13];
    const float* se_Wih1 = (const float*)d_in[14], *se_Whh1 = (const float*)d_in[15];
    const float* se_bih1 = (const float*)d_in[16], *se_bhh1 = (const float*)d_in[17];

    // ---- arenas (142.2 MB total; proven-safe < 149 MB) ----
    char* ws = (char*)d_ws;
    const size_t szA = 9216000;    // words bf16 [Nw,300]                (persists)
    const size_t szB = 46080000;   // y0w bf16 [T*Nw,150] -> y0s bf16 [S*B,1400]=43.0MB
    const size_t szCDE = 68472000; // word: embW 27.0 | gh_w 27.648 | xw_w1 13.824
                                   // sent: xw_chunk bf16 [2,CH,B,Gs] = 64.512MB
    const size_t szF = 9216000;    // h_w0 f32 [2,Nw,75] -> gh_s f32 [2,B,2100]=2.15MB
    const size_t szG = 9216000;    // h_w1              -> h_s0 + h_s1 (0.717MB each)
    char* pA = ws;
    char* pB = pA + szA;
    char* pC = pB + szB;
    char* pF = pC + szCDE;
    char* pG = pF + szF;
    const size_t total = szA + szB + szCDE + szF + szG;  // 142,200,000

    bf16*  words  = (bf16*)pA;
    bf16*  y0w    = (bf16*)pB;
    bf16*  y0s    = (bf16*)pB;
    bf16*  embW   = (bf16*)pC;                       // word phase
    float* gh_w   = (float*)(pC + 27000000);
    bf16*  xw_w1  = (bf16*)(pC + 27000000 + 27648000);
    bf16*  xw_ch  = (bf16*)pC;                       // sentence phase (overlays)
    float* h_w0   = (float*)pF;
    float* gh_s   = (float*)pF;
    float* h_w1   = (float*)pG;
    float* h_s0   = (float*)pG;
    float* h_s1   = (float*)(pG + 2ull * B * HS * sizeof(float));

    hipMemsetAsync(ws, 0, total, stream);  // poison kill + h0 = 0

    auto grid = [](int M, int Nc) {
        return dim3((Nc + TN - 1) / TN, (M + TM - 1) / TM, 2);
    };

    // ===================== word encoder =====================
    // embW[d] = emb @ Wih0[d]^T : [V,E] @ [Gw,E]^T -> [2,V,Gw]
    gemm_aw<float, float, bf16><<<grid(V, Gw), 256, 0, stream>>>(
        emb, 0, we_Wih0, (long)Gw * E, embW, (long)V * Gw, V, Gw, E);
    // ---- layer 0 ----
    for (int k = 0; k < T; ++k) {
        gemm_aw<float, float, float><<<grid(Nw, Gw), 256, 0, stream>>>(
            h_w0, (long)Nw * HW, we_Whh0, (long)Gw * HW, gh_w, (long)Nw * Gw, Nw, Gw, HW);
        long tot = 2ll * Nw * HW;
        gru_step_word0<<<(tot + 255) / 256, 256, 0, stream>>>(
            x, embW, gh_w, we_bih0, we_bhh0, h_w0, y0w, S, T, B, V, HW, k);
    }
    // ---- layer 1 ----
    for (int k = 0; k < T; ++k) {
        gemm_aw<bf16, float, bf16><<<grid(Nw, Gw), 256, 0, stream>>>(
            y0w + (long)k * Nw * 2 * HW, (long)(T - 1 - 2 * k) * Nw * 2 * HW,
            we_Wih1, (long)Gw * (2 * HW), xw_w1, (long)Nw * Gw, Nw, Gw, 2 * HW);
        gemm_aw<float, float, float><<<grid(Nw, Gw), 256, 0, stream>>>(
            h_w1, (long)Nw * HW, we_Whh1, (long)Gw * HW, gh_w, (long)Nw * Gw, Nw, Gw, HW);
        long tot = 2ll * Nw * HW;
        gru_step1<<<(tot + 255) / 256, 256, 0, stream>>>(
            xw_w1, k, T - 1 - k, 1, gh_w, we_bih1, we_bhh1, h_w1, nullptr, Nw, HW, T, k);
    }
    {
        long tot = (long)Nw * 4 * HW;
        concat4<bf16><<<(tot + 255) / 256, 256, 0, stream>>>(h_w0, h_w1, words, Nw, HW);
    }

    // ===================== sentence encoder =====================
    // h_s0/h_s1 overlay h_w1's arena (dead after concat) -> re-zero.
    hipMemsetAsync(h_s0, 0, 2ull * B * HS * sizeof(float), stream);
    hipMemsetAsync(h_s1, 0, 2ull * B * HS * sizeof(float), stream);

    dim3 sg((Gs + TN2 - 1) / TN2, B / TM2, 2);   // 33 x 4 x 2 = 264 blocks

    // ---- layer 0: 2 chunks of 60 steps; xw batched per chunk ----
    for (int c = 0; c < 2; ++c) {
        int tb0 = c * CH;               // fwd t-range  [tb0, tb0+CH)
        int tb1 = S - c * CH - CH;      // bwd t-range  [tb1, tb1+CH)
        gemm_aw<bf16, float, bf16><<<grid(CH * B, Gs), 256, 0, stream>>>(
            words + (long)tb0 * B * (4 * HW), (long)(tb1 - tb0) * B * (4 * HW),
            se_Wih0, (long)Gs * (4 * HW), xw_ch, (long)CH * B * Gs, CH * B, Gs, 4 * HW);
        for (int k = c * CH; k < c * CH + CH; ++k) {
            gemm_step<<<sg, 256, 0, stream>>>(
                h_s0, (long)B * HS, se_Whh0, (long)Gs * HS, gh_s, (long)B * Gs, B, Gs, HS);
            long tot = 2ll * B * HS;
            gru_step1<<<(tot + 255) / 256, 256, 0, stream>>>(
                xw_ch, tb0, tb1, CH, gh_s, se_bih0, se_bhh0, h_s0, y0s, B, HS, S, k);
        }
    }
    // ---- layer 1: same chunking; input = y0s ----
    for (int c = 0; c < 2; ++c) {
        int tb0 = c * CH;
        int tb1 = S - c * CH - CH;
        gemm_aw<bf16, float, bf16><<<grid(CH * B, Gs), 256, 0, stream>>>(
            y0s + (long)tb0 * B * (2 * HS), (long)(tb1 - tb0) * B * (2 * HS),
            se_Wih1, (long)Gs * (2 * HS), xw_ch, (long)CH * B * Gs, CH * B, Gs, 2 * HS);
        for (int k = c * CH; k < c * CH + CH; ++k) {
            gemm_step<<<sg, 256, 0, stream>>>(
                h_s1, (long)B * HS, se_Whh1, (long)Gs * HS, gh_s, (long)B * Gs, B, Gs, HS);
            long tot = 2ll * B * HS;
            gru_step1<<<(tot + 255) / 256, 256, 0, stream>>>(
                xw_ch, tb0, tb1, CH, gh_s, se_bih1, se_bhh1, h_s1, nullptr, B, HS, S, k);
        }
    }

    // out[1, B, 4*HS] = [sf0 | sb0 | sf1 | sb1]  (float32)
    {
        long tot = (long)B * 4 * HS;
        concat4<float><<<(tot + 255) / 256, 256, 0, stream>>>(h_s0, h_s1, (float*)d_out, B, HS);
    }
}